// Round 3
// baseline (23220.439 us; speedup 1.0000x reference)
//
#include <hip/hip_runtime.h>
#include <math.h>

// ---------------------------------------------------------------------------
// CurvePredictor R3: weight-stationary persistent-group design.
// 256 blocks x 256 threads. Groups of 8 same-XCD blocks (b%8) own 64 batch
// rows; each member holds 1/8 of the recurrent weights (its 32 hidden cols'
// gate rows for Whh0/Wih1/Whh1, 96 VGPRs/lane) + W3/W4 fragments in REGISTERS.
// Per step members exchange bf16 h-slices via d_ws with fence+atomic counters.
// MFMA transposed: A=weights (m=gate-rows), B=h (n=batch). Lane (m16,q) of
// wave w owns hid = m*32+w*8+ct*4+q: its 4 acc regs = the 4 gates (i,f,g,o).
// Whh0*h0(t) fused into step t's h0-sweep (acc0n) -> gates0 phase is gemm-free.
// Decoder (W3->gelu->W4) runs fused with lag 1.
// ---------------------------------------------------------------------------

typedef short s8v __attribute__((ext_vector_type(8)));   // 8 x bf16
typedef float f4v __attribute__((ext_vector_type(4)));   // 4 x f32

// ws layout (bytes):
//   [0, 2232320)  bf16 weights (shorts):
//     [0,262144) Wih0 interleaved (row'=hid*4+gate), [262144,524288) Whh0,
//     [524288,786432) Wih1, [786432,1048576) Whh1,
//     [1048576,1081344) W3[128][256], [1081344,1083392) W4 padded [16][128],
//     [1083392,1116160) W2[256][128]
#define OFF_B0I  2232320u   // bias0i f32[1024] (bih0+bhh0, interleaved idx)
#define OFF_B1I  2236416u   // bias1i f32[1024]
#define OFF_CNT  2240512u   // u32[64]: cnt0[32], cnt1[32]
#define OFF_HX0  2244608u   // bf16 [32 gid][2 slot][8 member][64 b][32 c]
#define OFF_HX1  4341760u   // same

__device__ __forceinline__ f4v mfma16(s8v a, s8v b, f4v c){
  return __builtin_amdgcn_mfma_f32_16x16x32_bf16(a, b, c, 0, 0, 0);
}
__device__ __forceinline__ short f2bf(float f){
  unsigned u = __float_as_uint(f);
  u = u + 0x7FFFu + ((u >> 16) & 1u);
  return (short)(u >> 16);
}
__device__ __forceinline__ float bf2f(short s){
  unsigned u = ((unsigned)(unsigned short)s) << 16;
  return __uint_as_float(u);
}
__device__ __forceinline__ float sigm(float x){ return 1.0f / (1.0f + __expf(-x)); }
__device__ __forceinline__ float tnh(float x){
  x = fminf(15.0f, fmaxf(-15.0f, x));
  float e = __expf(2.0f * x);
  return (e - 1.0f) / (e + 1.0f);
}
__device__ __forceinline__ float gelu(float v){
  return 0.5f * v * (1.0f + erff(v * 0.70710678118654752440f));
}

__global__ void prep_kernel(
    const float* __restrict__ Wih0, const float* __restrict__ Whh0,
    const float* __restrict__ Wih1, const float* __restrict__ Whh1,
    const float* __restrict__ W3,   const float* __restrict__ W4,
    const float* __restrict__ W2,
    const float* __restrict__ bih0, const float* __restrict__ bhh0,
    const float* __restrict__ bih1, const float* __restrict__ bhh1,
    short* __restrict__ wsb, float* __restrict__ b0i, float* __restrict__ b1i,
    unsigned* __restrict__ cnt)
{
  const int i = blockIdx.x * 256 + threadIdx.x;
  if (i < 1024){
    int hid = i >> 2, g = i & 3, n = g * 256 + hid;
    b0i[i] = bih0[n] + bhh0[n];
    b1i[i] = bih1[n] + bhh1[n];
  }
  if (i < 64) cnt[i] = 0u;
  if (i >= 1116160) return;
  float v;
  if (i < 1048576){
    const int seg  = i >> 18;
    const int j    = i & 262143;
    const int rowp = j >> 8;         // interleaved row: hid*4 + gate
    const int col  = j & 255;
    const int g    = rowp & 3;
    const int hid  = rowp >> 2;
    const int src  = (g * 256 + hid) * 256 + col;
    const float* mt = (seg == 0) ? Wih0 : (seg == 1) ? Whh0 : (seg == 2) ? Wih1 : Whh1;
    v = mt[src];
  } else if (i < 1081344){
    v = W3[i - 1048576];
  } else if (i < 1083392){
    const int j = i - 1081344;
    const int r = j >> 7, c = j & 127;
    v = (r < 2) ? W4[r * 128 + c] : 0.0f;
  } else {
    v = W2[i - 1083392];
  }
  wsb[i] = f2bf(v);
}

__global__ __launch_bounds__(256, 1) void curve_main(
    const float* __restrict__ x,
    const float* __restrict__ W1, const float* __restrict__ b1,
    const float* __restrict__ g1, const float* __restrict__ be1,
    const float* __restrict__ b2, const float* __restrict__ g2,
    const float* __restrict__ be2,
    const float* __restrict__ b3, const float* __restrict__ b4,
    const short* __restrict__ wsb,
    const float* __restrict__ b0i, const float* __restrict__ b1i,
    unsigned* __restrict__ cnt, short* __restrict__ hx0, short* __restrict__ hx1,
    float* __restrict__ out)
{
  const int tid  = threadIdx.x;
  const int w    = tid >> 6;        // wave 0..3
  const int lane = tid & 63;
  const int q    = lane >> 4;
  const int m16  = lane & 15;
  const int bidx = blockIdx.x;
  const int m    = (bidx >> 3) & 7;               // member within group
  const int gid  = (bidx >> 6) * 8 + (bidx & 7);  // group 0..31 (same-XCD heur.)
  const int row0 = gid * 64;

  __shared__ __align__(16) short h0loc[64 * 264];
  __shared__ __align__(16) short h1loc[64 * 264];
  __shared__ __align__(16) float xpl[64 * 132];   // xp0; aliased ytmp/gtmp in init
  __shared__ __align__(16) short dloc[64 * 136];  // decoder d; aliased LN scratch

  short* hx0g = hx0 + gid * 32768;
  short* hx1g = hx1 + gid * 32768;
  unsigned* cnt0p = cnt + gid;
  unsigned* cnt1p = cnt + 32 + gid;

  // ---------------- persistent weight fragments (registers) ----------------
  s8v w0f[2][8], wi1f[2][8], wh1f[2][8], w3f[2][8], w4f[4];
  {
    const s8v* p0 = (const s8v*)(wsb +  262144) + (m*128 + w*32 + m16)*32 + q;
    const s8v* p1 = (const s8v*)(wsb +  524288) + (m*128 + w*32 + m16)*32 + q;
    const s8v* p2 = (const s8v*)(wsb +  786432) + (m*128 + w*32 + m16)*32 + q;
    const s8v* p3 = (const s8v*)(wsb + 1048576) + (w*32 + m16)*32 + q;
    #pragma unroll
    for (int ct = 0; ct < 2; ct++)
      #pragma unroll
      for (int kk = 0; kk < 8; kk++){
        w0f [ct][kk] = p0[ct*512 + kk*4];
        wi1f[ct][kk] = p1[ct*512 + kk*4];
        wh1f[ct][kk] = p2[ct*512 + kk*4];
        w3f [ct][kk] = p3[ct*512 + kk*4];
      }
    const s8v* p4 = (const s8v*)(wsb + 1081344) + m16*16 + q;
    #pragma unroll
    for (int kk = 0; kk < 4; kk++) w4f[kk] = p4[kk*4];
  }

  // ---------------- encoder stage 1: x -> gelu(W1) -> LN1 -> yb (h1loc) ----
  {
    const int bb = tid >> 2, qq = tid & 3;
    float xv[5];
    #pragma unroll
    for (int k = 0; k < 5; k++) xv[k] = x[(row0 + bb)*5 + k];
    float* yt = xpl;
    float s = 0.f, s2 = 0.f;
    for (int o = qq*32; o < qq*32 + 32; o++){
      float a = b1[o];
      #pragma unroll
      for (int k = 0; k < 5; k++) a += xv[k] * W1[o*5 + k];
      a = gelu(a);
      yt[bb*132 + o] = a; s += a; s2 += a*a;
    }
    float* lp = (float*)dloc;
    lp[(bb*4 + qq)*2] = s; lp[(bb*4 + qq)*2 + 1] = s2;
  }
  __syncthreads();
  if (tid < 64){
    float* lp = (float*)dloc; float s = 0.f, s2 = 0.f;
    #pragma unroll
    for (int j = 0; j < 4; j++){ s += lp[(tid*4 + j)*2]; s2 += lp[(tid*4 + j)*2 + 1]; }
    float mean = s * (1.0f/128.0f);
    float var  = s2 * (1.0f/128.0f) - mean*mean;
    lp[512 + tid*2] = mean; lp[512 + tid*2 + 1] = rsqrtf(var + 1e-5f);
  }
  __syncthreads();
  {
    const int bb = tid >> 2, qq = tid & 3;
    float* lp = (float*)dloc;
    float mean = lp[512 + bb*2], inv = lp[512 + bb*2 + 1];
    float* yt = xpl;
    for (int o = qq*32; o < qq*32 + 32; o++){
      float v = (yt[bb*132 + o] - mean) * inv * g1[o] + be1[o];
      h1loc[bb*264 + o] = f2bf(v);
    }
  }
  __syncthreads();
  // ------------- encoder stage 2 (MFMA): gelu(yb@W2^T+b2) -> gtmp ----------
  {
    short* gtmp = (short*)xpl;     // ytmp dead
    const s8v* pw2 = (const s8v*)(wsb + 1083392);
    #pragma unroll 1
    for (int ct = 0; ct < 4; ct++){
      const int colb = w*64 + ct*16;
      s8v wf[4];
      #pragma unroll
      for (int kk = 0; kk < 4; kk++) wf[kk] = pw2[(colb + m16)*16 + kk*4 + q];
      const float4 bv = *(const float4*)&b2[colb + q*4];
      f4v ac[4];
      #pragma unroll
      for (int rt = 0; rt < 4; rt++){ f4v t = {bv.x, bv.y, bv.z, bv.w}; ac[rt] = t; }
      #pragma unroll
      for (int kk = 0; kk < 4; kk++)
        #pragma unroll
        for (int rt = 0; rt < 4; rt++){
          s8v bf = *(const s8v*)&h1loc[(rt*16 + m16)*264 + kk*32 + q*8];
          ac[rt] = mfma16(wf[kk], bf, ac[rt]);
        }
      #pragma unroll
      for (int rt = 0; rt < 4; rt++){
        short4 s4;
        s4.x = f2bf(gelu(ac[rt][0])); s4.y = f2bf(gelu(ac[rt][1]));
        s4.z = f2bf(gelu(ac[rt][2])); s4.w = f2bf(gelu(ac[rt][3]));
        *(short4*)&gtmp[(rt*16 + m16)*264 + colb + q*4] = s4;
      }
    }
  }
  __syncthreads();
  // ---------------- LN2 -> enc bf16 -> h0loc ----------------
  {
    const int bb = tid >> 2, part = tid & 3;
    short* gtmp = (short*)xpl;
    float s = 0.f, s2 = 0.f;
    for (int o = part*64; o < part*64 + 64; o++){
      float v = bf2f(gtmp[bb*264 + o]); s += v; s2 += v*v;
    }
    float* lp = (float*)dloc;
    lp[(bb*4 + part)*2] = s; lp[(bb*4 + part)*2 + 1] = s2;
  }
  __syncthreads();
  if (tid < 64){
    float* lp = (float*)dloc; float s = 0.f, s2 = 0.f;
    #pragma unroll
    for (int j = 0; j < 4; j++){ s += lp[(tid*4 + j)*2]; s2 += lp[(tid*4 + j)*2 + 1]; }
    float mean = s * (1.0f/256.0f);
    float var  = s2 * (1.0f/256.0f) - mean*mean;
    lp[512 + tid*2] = mean; lp[512 + tid*2 + 1] = rsqrtf(var + 1e-5f);
  }
  __syncthreads();
  {
    const int bb = tid >> 2, part = tid & 3;
    float* lp = (float*)dloc;
    float mean = lp[512 + bb*2], inv = lp[512 + bb*2 + 1];
    short* gtmp = (short*)xpl;
    for (int o = part*64; o < part*64 + 64; o++){
      float v = bf2f(gtmp[bb*264 + o]);
      h0loc[bb*264 + o] = f2bf((v - mean) * inv * g2[o] + be2[o]);
    }
  }
  __syncthreads();
  // ---------------- xp0 = enc @ Wih0_slice^T + bias0 -> xpl ----------------
  {
    const s8v* pwi0 = (const s8v*)(wsb) + (m*128 + w*32 + m16)*32 + q;
    #pragma unroll 1
    for (int ct = 0; ct < 2; ct++){
      const float4 bv = *(const float4*)&b0i[m*128 + w*32 + ct*16 + q*4];
      f4v xa[4];
      #pragma unroll
      for (int rt = 0; rt < 4; rt++){ f4v t = {bv.x, bv.y, bv.z, bv.w}; xa[rt] = t; }
      #pragma unroll
      for (int kk = 0; kk < 8; kk++){
        s8v af = pwi0[ct*512 + kk*4];
        #pragma unroll
        for (int rt = 0; rt < 4; rt++){
          s8v bf = *(const s8v*)&h0loc[(rt*16 + m16)*264 + kk*32 + q*8];
          xa[rt] = mfma16(af, bf, xa[rt]);
        }
      }
      #pragma unroll
      for (int rt = 0; rt < 4; rt++){
        float4 o4 = {xa[rt][0], xa[rt][1], xa[rt][2], xa[rt][3]};
        *(float4*)&xpl[(rt*16 + m16)*132 + w*32 + ct*16 + q*4] = o4;
      }
    }
  }
  __syncthreads();
  for (int i = tid; i < 64*264; i += 256){ h0loc[i] = 0; h1loc[i] = 0; }

  f4v acc0n[2][4], acc1[2][4], accd[2][4];
  float c0[2][4], c1[2][4];
  #pragma unroll
  for (int ct = 0; ct < 2; ct++)
    #pragma unroll
    for (int rt = 0; rt < 4; rt++){
      f4v z = {0.f, 0.f, 0.f, 0.f};
      acc0n[ct][rt] = z; c0[ct][rt] = 0.f; c1[ct][rt] = 0.f;
    }
  float4 bs1v[2], b3v[2];
  #pragma unroll
  for (int ct = 0; ct < 2; ct++){
    bs1v[ct] = *(const float4*)&b1i[m*128 + w*32 + ct*16 + q*4];
    b3v[ct]  = *(const float4*)&b3[w*32 + ct*16 + q*4];
  }
  const float b4x = b4[0], b4y = b4[1];
  __syncthreads();

  // --------------------------- recurrence over T ---------------------------
  #pragma unroll 1
  for (int t = 0; t < 256; t++){
    const int slot = t & 1;
    // ---- P0: gates0 = xp + acc0n -> c0,h0 -> own cols of h0loc ----
    #pragma unroll
    for (int ct = 0; ct < 2; ct++)
      #pragma unroll
      for (int rt = 0; rt < 4; rt++){
        const float4 xv = *(const float4*)&xpl[(rt*16 + m16)*132 + w*32 + ct*16 + q*4];
        f4v gg = acc0n[ct][rt];
        float ii = sigm(gg[0] + xv.x);
        float ff = sigm(gg[1] + xv.y);
        float g_ = tnh (gg[2] + xv.z);
        float oo = sigm(gg[3] + xv.w);
        c0[ct][rt] = ff * c0[ct][rt] + ii * g_;
        float hh = oo * tnh(c0[ct][rt]);
        h0loc[(rt*16 + m16)*264 + m*32 + w*8 + ct*4 + q] = f2bf(hh);
        f4v z = {0.f, 0.f, 0.f, 0.f};
        acc0n[ct][rt] = z;
      }
    __syncthreads();
    { // coalesced exchange write of own h0 slice
      const int bb = tid >> 2, jj = tid & 3;
      *(s8v*)&hx0g[((slot*8 + m)*64 + bb)*32 + jj*8] =
          *(const s8v*)&h0loc[bb*264 + m*32 + jj*8];
    }
    __threadfence();
    __syncthreads();
    if (tid == 0)
      __hip_atomic_fetch_add(cnt0p, 1u, __ATOMIC_RELEASE, __HIP_MEMORY_SCOPE_AGENT);

    // ---- overlap window: h1 copy + h1-sweep + decoder(t-1) ----
    if (tid == 0){
      const unsigned tgt = 8u * (unsigned)t;
      while (__hip_atomic_load(cnt1p, __ATOMIC_ACQUIRE, __HIP_MEMORY_SCOPE_AGENT) < tgt)
        __builtin_amdgcn_s_sleep(1);
    }
    __syncthreads();
    __threadfence();
    if (t > 0){
      const int ps = (t - 1) & 1;
      const int bb = tid & 63;
      #pragma unroll
      for (int pass = 0; pass < 2; pass++){
        const int mm = (tid >> 6) + pass*4;
        if (mm != m){
          #pragma unroll
          for (int jj = 0; jj < 4; jj++)
            *(s8v*)&h1loc[bb*264 + mm*32 + jj*8] =
                *(const s8v*)&hx1g[((ps*8 + mm)*64 + bb)*32 + jj*8];
        }
      }
    }
    __syncthreads();
    // init acc1 with bias1, accd with b3; sweep h1(t-1): Whh1 + W3
    #pragma unroll
    for (int ct = 0; ct < 2; ct++)
      #pragma unroll
      for (int rt = 0; rt < 4; rt++){
        f4v a = {bs1v[ct].x, bs1v[ct].y, bs1v[ct].z, bs1v[ct].w};
        f4v d = {b3v[ct].x,  b3v[ct].y,  b3v[ct].z,  b3v[ct].w};
        acc1[ct][rt] = a; accd[ct][rt] = d;
      }
    #pragma unroll
    for (int kk = 0; kk < 8; kk++){
      s8v bf[4];
      #pragma unroll
      for (int rt = 0; rt < 4; rt++)
        bf[rt] = *(const s8v*)&h1loc[(rt*16 + m16)*264 + kk*32 + q*8];
      #pragma unroll
      for (int rt = 0; rt < 4; rt++)
        #pragma unroll
        for (int ct = 0; ct < 2; ct++){
          acc1[ct][rt] = mfma16(wh1f[ct][kk], bf[rt], acc1[ct][rt]);
          accd[ct][rt] = mfma16(w3f [ct][kk], bf[rt], accd[ct][rt]);
        }
    }
    if (t > 0){ // decoder stage 1 for output step t-1
      #pragma unroll
      for (int ct = 0; ct < 2; ct++)
        #pragma unroll
        for (int rt = 0; rt < 4; rt++){
          f4v dv = accd[ct][rt];
          short4 s4;
          s4.x = f2bf(gelu(dv[0])); s4.y = f2bf(gelu(dv[1]));
          s4.z = f2bf(gelu(dv[2])); s4.w = f2bf(gelu(dv[3]));
          *(short4*)&dloc[(rt*16 + m16)*136 + w*32 + ct*16 + q*4] = s4;
        }
      __syncthreads();
      if (w == 0){
        #pragma unroll
        for (int rt = 0; rt < 4; rt++){
          f4v ao = {0.f, 0.f, 0.f, 0.f};
          #pragma unroll
          for (int kk = 0; kk < 4; kk++){
            s8v bf = *(const s8v*)&dloc[(rt*16 + m16)*136 + kk*32 + q*8];
            ao = mfma16(w4f[kk], bf, ao);
          }
          if (q == 0){
            float2 o2; o2.x = ao[0] + b4x; o2.y = ao[1] + b4y;
            *(float2*)&out[((row0 + rt*16 + m16)*256 + (t - 1))*2] = o2;
          }
        }
      }
    }

    // ---- join on h0(t), copy, h0-sweep (Wih1 + Whh0-for-next) ----
    if (tid == 0){
      const unsigned tgt = 8u * (unsigned)(t + 1);
      while (__hip_atomic_load(cnt0p, __ATOMIC_ACQUIRE, __HIP_MEMORY_SCOPE_AGENT) < tgt)
        __builtin_amdgcn_s_sleep(1);
    }
    __syncthreads();
    __threadfence();
    {
      const int bb = tid & 63;
      #pragma unroll
      for (int pass = 0; pass < 2; pass++){
        const int mm = (tid >> 6) + pass*4;
        if (mm != m){
          #pragma unroll
          for (int jj = 0; jj < 4; jj++)
            *(s8v*)&h0loc[bb*264 + mm*32 + jj*8] =
                *(const s8v*)&hx0g[((slot*8 + mm)*64 + bb)*32 + jj*8];
        }
      }
    }
    __syncthreads();
    #pragma unroll
    for (int kk = 0; kk < 8; kk++){
      s8v bf[4];
      #pragma unroll
      for (int rt = 0; rt < 4; rt++)
        bf[rt] = *(const s8v*)&h0loc[(rt*16 + m16)*264 + kk*32 + q*8];
      #pragma unroll
      for (int rt = 0; rt < 4; rt++)
        #pragma unroll
        for (int ct = 0; ct < 2; ct++){
          acc1 [ct][rt] = mfma16(wi1f[ct][kk], bf[rt], acc1 [ct][rt]);
          acc0n[ct][rt] = mfma16(w0f [ct][kk], bf[rt], acc0n[ct][rt]);
        }
    }
    // ---- gates1 -> c1,h1 -> own cols of h1loc ----
    #pragma unroll
    for (int ct = 0; ct < 2; ct++)
      #pragma unroll
      for (int rt = 0; rt < 4; rt++){
        f4v gg = acc1[ct][rt];
        float ii = sigm(gg[0]);
        float ff = sigm(gg[1]);
        float g_ = tnh (gg[2]);
        float oo = sigm(gg[3]);
        c1[ct][rt] = ff * c1[ct][rt] + ii * g_;
        float hh = oo * tnh(c1[ct][rt]);
        h1loc[(rt*16 + m16)*264 + m*32 + w*8 + ct*4 + q] = f2bf(hh);
      }
    __syncthreads();
    { // exchange write own h1 slice
      const int bb = tid >> 2, jj = tid & 3;
      *(s8v*)&hx1g[((slot*8 + m)*64 + bb)*32 + jj*8] =
          *(const s8v*)&h1loc[bb*264 + m*32 + jj*8];
    }
    __threadfence();
    __syncthreads();
    if (tid == 0)
      __hip_atomic_fetch_add(cnt1p, 1u, __ATOMIC_RELEASE, __HIP_MEMORY_SCOPE_AGENT);
  }

  // --------------------------- tail: decode t=255 --------------------------
  if (tid == 0){
    while (__hip_atomic_load(cnt1p, __ATOMIC_ACQUIRE, __HIP_MEMORY_SCOPE_AGENT) < 2048u)
      __builtin_amdgcn_s_sleep(1);
  }
  __syncthreads();
  __threadfence();
  {
    const int bb = tid & 63;
    #pragma unroll
    for (int pass = 0; pass < 2; pass++){
      const int mm = (tid >> 6) + pass*4;
      if (mm != m){
        #pragma unroll
        for (int jj = 0; jj < 4; jj++)
          *(s8v*)&h1loc[bb*264 + mm*32 + jj*8] =
              *(const s8v*)&hx1g[((8 + mm)*64 + bb)*32 + jj*8];   // slot 1
      }
    }
  }
  __syncthreads();
  #pragma unroll
  for (int ct = 0; ct < 2; ct++)
    #pragma unroll
    for (int rt = 0; rt < 4; rt++){
      f4v d = {b3v[ct].x, b3v[ct].y, b3v[ct].z, b3v[ct].w};
      accd[ct][rt] = d;
    }
  #pragma unroll
  for (int kk = 0; kk < 8; kk++){
    s8v bf[4];
    #pragma unroll
    for (int rt = 0; rt < 4; rt++)
      bf[rt] = *(const s8v*)&h1loc[(rt*16 + m16)*264 + kk*32 + q*8];
    #pragma unroll
    for (int rt = 0; rt < 4; rt++)
      #pragma unroll
      for (int ct = 0; ct < 2; ct++)
        accd[ct][rt] = mfma16(w3f[ct][kk], bf[rt], accd[ct][rt]);
  }
  #pragma unroll
  for (int ct = 0; ct < 2; ct++)
    #pragma unroll
    for (int rt = 0; rt < 4; rt++){
      f4v dv = accd[ct][rt];
      short4 s4;
      s4.x = f2bf(gelu(dv[0])); s4.y = f2bf(gelu(dv[1]));
      s4.z = f2bf(gelu(dv[2])); s4.w = f2bf(gelu(dv[3]));
      *(short4*)&dloc[(rt*16 + m16)*136 + w*32 + ct*16 + q*4] = s4;
    }
  __syncthreads();
  if (w == 0){
    #pragma unroll
    for (int rt = 0; rt < 4; rt++){
      f4v ao = {0.f, 0.f, 0.f, 0.f};
      #pragma unroll
      for (int kk = 0; kk < 4; kk++){
        s8v bf = *(const s8v*)&dloc[(rt*16 + m16)*136 + kk*32 + q*8];
        ao = mfma16(w4f[kk], bf, ao);
      }
      if (q == 0){
        float2 o2; o2.x = ao[0] + b4x; o2.y = ao[1] + b4y;
        *(float2*)&out[((row0 + rt*16 + m16)*256 + 255)*2] = o2;
      }
    }
  }
}

extern "C" void kernel_launch(void* const* d_in, const int* in_sizes, int n_in,
                              void* d_out, int out_size, void* d_ws, size_t ws_size,
                              hipStream_t stream)
{
  const float* x    = (const float*)d_in[0];
  const float* W1   = (const float*)d_in[1];
  const float* b1   = (const float*)d_in[2];
  const float* g1   = (const float*)d_in[3];
  const float* be1  = (const float*)d_in[4];
  const float* W2   = (const float*)d_in[5];
  const float* b2   = (const float*)d_in[6];
  const float* g2   = (const float*)d_in[7];
  const float* be2  = (const float*)d_in[8];
  const float* Wih0 = (const float*)d_in[9];
  const float* Whh0 = (const float*)d_in[10];
  const float* bih0 = (const float*)d_in[11];
  const float* bhh0 = (const float*)d_in[12];
  const float* Wih1 = (const float*)d_in[13];
  const float* Whh1 = (const float*)d_in[14];
  const float* bih1 = (const float*)d_in[15];
  const float* bhh1 = (const float*)d_in[16];
  const float* W3   = (const float*)d_in[17];
  const float* b3   = (const float*)d_in[18];
  const float* W4   = (const float*)d_in[19];
  const float* b4   = (const float*)d_in[20];

  short*    wsb  = (short*)d_ws;
  float*    b0iv = (float*)((char*)d_ws + OFF_B0I);
  float*    b1iv = (float*)((char*)d_ws + OFF_B1I);
  unsigned* cnt  = (unsigned*)((char*)d_ws + OFF_CNT);
  short*    hx0  = (short*)((char*)d_ws + OFF_HX0);
  short*    hx1  = (short*)((char*)d_ws + OFF_HX1);

  prep_kernel<<<4360, 256, 0, stream>>>(Wih0, Whh0, Wih1, Whh1, W3, W4, W2,
                                        bih0, bhh0, bih1, bhh1, wsb, b0iv, b1iv, cnt);
  curve_main<<<256, 256, 0, stream>>>(x, W1, b1, g1, be1, b2, g2, be2, b3, b4,
                                      wsb, b0iv, b1iv, cnt, hx0, hx1,
                                      (float*)d_out);
}

// Round 4
// 16118.399 us; speedup vs baseline: 1.4406x; 1.4406x over previous
//
#include <hip/hip_runtime.h>
#include <math.h>

// ---------------------------------------------------------------------------
// CurvePredictor R4: streaming weights + deep register prefetch, no cross-
// block sync. 64 blocks x 512 threads (8 waves, 2/SIMD, <=256 VGPR). Each
// block owns 32 batch rows for all T=256 steps; h0/h1 double-buffered in LDS.
// Weights (bf16, gate-interleaved) stream from L2 through a 3-slot register
// ring (prefetch distance 2 -> ~8KB in flight per wave) feeding MFMA B-ops.
// ---------------------------------------------------------------------------

typedef short s8v __attribute__((ext_vector_type(8)));   // 8 x bf16
typedef float f4v __attribute__((ext_vector_type(4)));   // 4 x f32

#define HSTR 264   // h-row stride in shorts (528B = 33*16 -> aligned, spread)
#define DSTR 136

__device__ __forceinline__ f4v mfma16(s8v a, s8v b, f4v c){
  return __builtin_amdgcn_mfma_f32_16x16x32_bf16(a, b, c, 0, 0, 0);
}
__device__ __forceinline__ short f2bf(float f){
  unsigned u = __float_as_uint(f);
  u = u + 0x7FFFu + ((u >> 16) & 1u);
  return (short)(u >> 16);
}
__device__ __forceinline__ float wred(float v){
  #pragma unroll
  for (int o = 32; o; o >>= 1) v += __shfl_xor(v, o);
  return v;
}
__device__ __forceinline__ float sigm(float x){ return 1.0f / (1.0f + __expf(-x)); }
__device__ __forceinline__ float tnh(float x){
  x = fminf(15.0f, fmaxf(-15.0f, x));
  float e = __expf(2.0f * x);
  return (e - 1.0f) / (e + 1.0f);
}
__device__ __forceinline__ float gelu(float v){
  return 0.5f * v * (1.0f + erff(v * 0.70710678118654752440f));
}

// ws layout (shorts):
//   [0,       262144)  Wih0 bf16, gate-interleaved: row' = hid*4 + gate
//   [262144,  524288)  Whh0 interleaved
//   [524288,  786432)  Wih1 interleaved
//   [786432, 1048576)  Whh1 interleaved
//   [1048576,1081344)  W3  row-major [128][256]
//   [1081344,1083392)  W4  zero-padded [16][128]
__global__ void prep_kernel(
    const float* __restrict__ Wih0, const float* __restrict__ Whh0,
    const float* __restrict__ Wih1, const float* __restrict__ Whh1,
    const float* __restrict__ W3,   const float* __restrict__ W4,
    short* __restrict__ wsb)
{
  const int i = blockIdx.x * 256 + threadIdx.x;
  if (i >= 1083392) return;
  float v;
  if (i < 1048576){
    const int seg  = i >> 18;
    const int j    = i & 262143;
    const int rowp = j >> 8;         // interleaved row: hid*4 + gate
    const int col  = j & 255;
    const int g    = rowp & 3;
    const int hid  = rowp >> 2;
    const int src  = (g * 256 + hid) * 256 + col;
    const float* mt = (seg == 0) ? Wih0 : (seg == 1) ? Whh0 : (seg == 2) ? Wih1 : Whh1;
    v = mt[src];
  } else if (i < 1081344){
    v = W3[i - 1048576];
  } else {
    const int j = i - 1081344;
    const int r = j >> 7, c = j & 127;
    v = (r < 2) ? W4[r * 128 + c] : 0.0f;
  }
  wsb[i] = f2bf(v);
}

// Streamed gemm over one 1024x256 interleaved matrix, this wave's 32-col
// slice. 16 steps (ct 0..1 x kk 0..7), 4 gate b-frags per step, 3-slot ring
// with prefetch distance 2. acc[rt][ct][g] += h[rt] @ W^T.
__device__ __forceinline__ void gemm_pipe(
    const short* __restrict__ hb, const s8v* __restrict__ pw,
    int m16, int q, f4v (&acc)[2][2][4])
{
  s8v rb[3][4];
  #pragma unroll
  for (int g = 0; g < 4; g++) rb[0][g] = pw[g * 32];        // s=0 (ct0,kk0)
  #pragma unroll
  for (int g = 0; g < 4; g++) rb[1][g] = pw[g * 32 + 4];    // s=1 (ct0,kk1)
  #pragma unroll
  for (int s = 0; s < 16; s++){
    const int ct = s >> 3, kk = s & 7;
    if (s < 14){
      const int s2 = s + 2, c2 = s2 >> 3, k2 = s2 & 7;
      #pragma unroll
      for (int g = 0; g < 4; g++)
        rb[s2 % 3][g] = pw[c2 * 2048 + g * 32 + k2 * 4];
    }
    const s8v af0 = *(const s8v*)&hb[ m16       * HSTR + kk * 32 + q * 8];
    const s8v af1 = *(const s8v*)&hb[(16 + m16) * HSTR + kk * 32 + q * 8];
    #pragma unroll
    for (int g = 0; g < 4; g++){
      acc[0][ct][g] = mfma16(af0, rb[s % 3][g], acc[0][ct][g]);
      acc[1][ct][g] = mfma16(af1, rb[s % 3][g], acc[1][ct][g]);
    }
  }
}

__global__ __launch_bounds__(512, 2) void curve_main(
    const float* __restrict__ x,
    const float* __restrict__ W1, const float* __restrict__ b1,
    const float* __restrict__ g1, const float* __restrict__ be1,
    const float* __restrict__ W2, const float* __restrict__ b2,
    const float* __restrict__ g2, const float* __restrict__ be2,
    const float* __restrict__ bih0, const float* __restrict__ bhh0,
    const float* __restrict__ bih1, const float* __restrict__ bhh1,
    const float* __restrict__ b3, const float* __restrict__ b4,
    const short* __restrict__ wsb,
    float* __restrict__ out)
{
  const int tid  = threadIdx.x;
  const int w    = tid >> 6;        // wave 0..7 <-> 32-col hidden slice
  const int lane = tid & 63;
  const int q    = lane >> 4;
  const int m16  = lane & 15;
  const int row0 = blockIdx.x * 32;

  __shared__ __align__(16) short h0buf[2][32 * HSTR];
  __shared__ __align__(16) short h1buf[2][32 * HSTR];
  __shared__ __align__(16) short dloc[32 * DSTR];

  // --------- encoder: wave w computes batch rows row0 + u*8 + w ------------
  #pragma unroll 1
  for (int u = 0; u < 4; u++){
    const int rr = u * 8 + w;
    const int r  = row0 + rr;
    float xv[5];
    #pragma unroll
    for (int k = 0; k < 5; k++) xv[k] = x[r * 5 + k];
    float a0 = b1[lane], a1 = b1[lane + 64];
    #pragma unroll
    for (int k = 0; k < 5; k++){
      a0 += xv[k] * W1[lane * 5 + k];
      a1 += xv[k] * W1[(lane + 64) * 5 + k];
    }
    a0 = gelu(a0); a1 = gelu(a1);
    float mean = wred(a0 + a1) * (1.0f / 128.0f);
    float d0 = a0 - mean, d1 = a1 - mean;
    float inv = rsqrtf(wred(d0 * d0 + d1 * d1) * (1.0f / 128.0f) + 1e-5f);
    float y0 = d0 * inv * g1[lane]      + be1[lane];
    float y1 = d1 * inv * g1[lane + 64] + be1[lane + 64];

    float acc2[4];
    #pragma unroll
    for (int uu = 0; uu < 4; uu++) acc2[uu] = b2[lane + 64 * uu];
    for (int k = 0; k < 64; k++){
      float v0 = __shfl(y0, k);
      float v1 = __shfl(y1, k);
      #pragma unroll
      for (int uu = 0; uu < 4; uu++){
        const float* wr = W2 + (lane + 64 * uu) * 128;
        acc2[uu] += v0 * wr[k] + v1 * wr[k + 64];
      }
    }
    #pragma unroll
    for (int uu = 0; uu < 4; uu++) acc2[uu] = gelu(acc2[uu]);
    float s = acc2[0] + acc2[1] + acc2[2] + acc2[3];
    mean = wred(s) * (1.0f / 256.0f);
    float vv = 0.0f;
    #pragma unroll
    for (int uu = 0; uu < 4; uu++){ float d = acc2[uu] - mean; vv += d * d; }
    inv = rsqrtf(wred(vv) * (1.0f / 256.0f) + 1e-5f);
    #pragma unroll
    for (int uu = 0; uu < 4; uu++){
      int c = lane + 64 * uu;
      float e = (acc2[uu] - mean) * inv * g2[c] + be2[c];
      h0buf[0][rr * HSTR + c] = f2bf(e);     // enc, A-operand layout
    }
  }
  __syncthreads();

  // per-lane weight bases (interleaved layout, hidc = w*32 + ct*16 + m16)
  const int hb0 = (w * 32 + m16) * 128 + q;         // s8v units, hidc base
  const s8v* pwi0 = (const s8v*)(wsb           ) + hb0;
  const s8v* pwh0 = (const s8v*)(wsb +  262144) + hb0;
  const s8v* pwi1 = (const s8v*)(wsb +  524288) + hb0;
  const s8v* pwh1 = (const s8v*)(wsb +  786432) + hb0;
  const s8v* pw3  = (const s8v*)(wsb + 1048576) + (w * 16 + m16) * 32 + q;
  const s8v* pw4  = (const s8v*)(wsb + 1081344) + m16 * 16 + q;

  // ---- xp0 = enc @ Wih0_slice^T + (bih0+bhh0), kept in registers ----
  f4v xp[2][2][4];
  #pragma unroll
  for (int ct = 0; ct < 2; ct++)
    #pragma unroll
    for (int g = 0; g < 4; g++){
      const int n = g * 256 + w * 32 + ct * 16 + m16;
      const float bi = bih0[n] + bhh0[n];
      f4v t = {bi, bi, bi, bi};
      xp[0][ct][g] = t; xp[1][ct][g] = t;
    }
  gemm_pipe(&h0buf[0][0], pwi0, m16, q, xp);
  __syncthreads();
  for (int i = tid; i < 32 * HSTR; i += 512){
    h0buf[0][i] = 0; h0buf[1][i] = 0; h1buf[0][i] = 0; h1buf[1][i] = 0;
  }

  float bs1[2][4];
  #pragma unroll
  for (int ct = 0; ct < 2; ct++)
    #pragma unroll
    for (int g = 0; g < 4; g++){
      const int n = g * 256 + w * 32 + ct * 16 + m16;
      bs1[ct][g] = bih1[n] + bhh1[n];
    }
  const float b3c = b3[w * 16 + m16];
  const float b4v = (m16 < 2) ? b4[m16] : 0.0f;
  float c0[2][2][4], c1[2][2][4];
  #pragma unroll
  for (int rt = 0; rt < 2; rt++)
    #pragma unroll
    for (int ct = 0; ct < 2; ct++)
      #pragma unroll
      for (int r = 0; r < 4; r++){ c0[rt][ct][r] = 0.f; c1[rt][ct][r] = 0.f; }
  __syncthreads();

  // --------------------------- recurrence over T ---------------------------
  #pragma unroll 1
  for (int t = 0; t < 256; t++){
    const short* h0in  = h0buf[t & 1];
    short*       h0out = h0buf[(t + 1) & 1];
    const short* h1in  = h1buf[t & 1];
    short*       h1out = h1buf[(t + 1) & 1];

    // ---- Phase A: gates0 = xp0 + h0_old @ Whh0^T -> c0,h0_new ----
    {
      f4v acc[2][2][4];
      #pragma unroll
      for (int rt = 0; rt < 2; rt++)
        #pragma unroll
        for (int ct = 0; ct < 2; ct++)
          #pragma unroll
          for (int g = 0; g < 4; g++) acc[rt][ct][g] = xp[rt][ct][g];
      gemm_pipe(h0in, pwh0, m16, q, acc);
      #pragma unroll
      for (int rt = 0; rt < 2; rt++)
        #pragma unroll
        for (int ct = 0; ct < 2; ct++)
          #pragma unroll
          for (int r = 0; r < 4; r++){
            float ii = sigm(acc[rt][ct][0][r]);
            float ff = sigm(acc[rt][ct][1][r]);
            float gg = tnh (acc[rt][ct][2][r]);
            float oo = sigm(acc[rt][ct][3][r]);
            c0[rt][ct][r] = ff * c0[rt][ct][r] + ii * gg;
            float hh = oo * tnh(c0[rt][ct][r]);
            h0out[(rt * 16 + q * 4 + r) * HSTR + w * 32 + ct * 16 + m16] = f2bf(hh);
          }
    }
    __syncthreads();                               // (1) h0_new visible

    // ---- Phase B: gates1 = bias1 + h0_new@Wih1^T + h1_old@Whh1^T ----
    {
      f4v acc[2][2][4];
      #pragma unroll
      for (int rt = 0; rt < 2; rt++)
        #pragma unroll
        for (int ct = 0; ct < 2; ct++)
          #pragma unroll
          for (int g = 0; g < 4; g++){
            f4v tv = {bs1[ct][g], bs1[ct][g], bs1[ct][g], bs1[ct][g]};
            acc[rt][ct][g] = tv;
          }
      gemm_pipe(h0out, pwi1, m16, q, acc);
      gemm_pipe(h1in,  pwh1, m16, q, acc);
      #pragma unroll
      for (int rt = 0; rt < 2; rt++)
        #pragma unroll
        for (int ct = 0; ct < 2; ct++)
          #pragma unroll
          for (int r = 0; r < 4; r++){
            float ii = sigm(acc[rt][ct][0][r]);
            float ff = sigm(acc[rt][ct][1][r]);
            float gg = tnh (acc[rt][ct][2][r]);
            float oo = sigm(acc[rt][ct][3][r]);
            c1[rt][ct][r] = ff * c1[rt][ct][r] + ii * gg;
            float hh = oo * tnh(c1[rt][ct][r]);
            h1out[(rt * 16 + q * 4 + r) * HSTR + w * 32 + ct * 16 + m16] = f2bf(hh);
          }
    }
    __syncthreads();                               // (2) h1_new visible

    // ---- Phase C: d = gelu(h1_new @ W3^T + b3), all 8 waves (128 cols) ----
    {
      f4v ad0 = {b3c, b3c, b3c, b3c};
      f4v ad1 = ad0;
      s8v r3[3];
      r3[0] = pw3[0]; r3[1] = pw3[4];
      #pragma unroll
      for (int kk = 0; kk < 8; kk++){
        if (kk < 6) r3[(kk + 2) % 3] = pw3[(kk + 2) * 4];
        const s8v af0 = *(const s8v*)&h1out[ m16       * HSTR + kk * 32 + q * 8];
        const s8v af1 = *(const s8v*)&h1out[(16 + m16) * HSTR + kk * 32 + q * 8];
        ad0 = mfma16(af0, r3[kk % 3], ad0);
        ad1 = mfma16(af1, r3[kk % 3], ad1);
      }
      #pragma unroll
      for (int r = 0; r < 4; r++){
        dloc[( q * 4 + r) * DSTR + w * 16 + m16]      = f2bf(gelu(ad0[r]));
        dloc[(16 + q * 4 + r) * DSTR + w * 16 + m16]  = f2bf(gelu(ad1[r]));
      }
    }
    __syncthreads();                               // (3) d visible

    // ---- Phase D: out = d @ W4^T + b4 (waves 0,1; rt = w) ----
    if (w < 2){
      const int rt = w;
      f4v ao = {0.f, 0.f, 0.f, 0.f};
      #pragma unroll
      for (int kk = 0; kk < 4; kk++){
        const s8v bw = pw4[kk * 4];
        const s8v af = *(const s8v*)&dloc[(rt * 16 + m16) * DSTR + kk * 32 + q * 8];
        ao = mfma16(af, bw, ao);
      }
      if (m16 < 2){
        #pragma unroll
        for (int r = 0; r < 4; r++)
          out[((row0 + rt * 16 + q * 4 + r) * 256 + t) * 2 + m16] = ao[r] + b4v;
      }
    }
  }
}

extern "C" void kernel_launch(void* const* d_in, const int* in_sizes, int n_in,
                              void* d_out, int out_size, void* d_ws, size_t ws_size,
                              hipStream_t stream)
{
  const float* x    = (const float*)d_in[0];
  const float* W1   = (const float*)d_in[1];
  const float* b1   = (const float*)d_in[2];
  const float* g1   = (const float*)d_in[3];
  const float* be1  = (const float*)d_in[4];
  const float* W2   = (const float*)d_in[5];
  const float* b2   = (const float*)d_in[6];
  const float* g2   = (const float*)d_in[7];
  const float* be2  = (const float*)d_in[8];
  const float* Wih0 = (const float*)d_in[9];
  const float* Whh0 = (const float*)d_in[10];
  const float* bih0 = (const float*)d_in[11];
  const float* bhh0 = (const float*)d_in[12];
  const float* Wih1 = (const float*)d_in[13];
  const float* Whh1 = (const float*)d_in[14];
  const float* bih1 = (const float*)d_in[15];
  const float* bhh1 = (const float*)d_in[16];
  const float* W3   = (const float*)d_in[17];
  const float* b3   = (const float*)d_in[18];
  const float* W4   = (const float*)d_in[19];
  const float* b4   = (const float*)d_in[20];

  short* wsb = (short*)d_ws;

  prep_kernel<<<4232, 256, 0, stream>>>(Wih0, Whh0, Wih1, Whh1, W3, W4, wsb);
  curve_main<<<64, 512, 0, stream>>>(x, W1, b1, g1, be1, W2, b2, g2, be2,
                                     bih0, bhh0, bih1, bhh1, b3, b4, wsb,
                                     (float*)d_out);
}

// Round 5
// 11702.634 us; speedup vs baseline: 1.9842x; 1.3773x over previous
//
#include <hip/hip_runtime.h>
#include <math.h>

// ---------------------------------------------------------------------------
// CurvePredictor R5: phase-split T-chunked recurrence, swizzled weights.
// 128 blocks x 1024 threads (16 waves, 4/SIMD), 16 batch rows per block.
// Per chunk of 8 timesteps:
//   phase A: 8 steps of layer-0 (stream ONLY Whh0, 0.5 MB) -> h0 chunk in LDS
//   phase B: 8 steps of layer-1 + decoder (stream Wih1+Whh1+W3, 1.1 MB)
// Hot weight set per XCD alternates 0.5 / 1.1 MB -> L2 resident.
// Weights pre-swizzled so each MFMA B-fragment load is one fully-coalesced
// 1 KB wave load (lane l reads 16B at base + l*16). Register rings with
// address-wrap keep prefetch alive across steps. No cross-block sync.
// ---------------------------------------------------------------------------

typedef short s8v __attribute__((ext_vector_type(8)));   // 8 x bf16
typedef float f4v __attribute__((ext_vector_type(4)));   // 4 x f32

#define HSTR 264            // LDS h-row stride in shorts (33*16B)
#define NH   (16 * HSTR)    // one h slot (16 rows)
#define DSTR 136

__device__ __forceinline__ f4v mfma16(s8v a, s8v b, f4v c){
  return __builtin_amdgcn_mfma_f32_16x16x32_bf16(a, b, c, 0, 0, 0);
}
__device__ __forceinline__ short f2bf(float f){
  unsigned u = __float_as_uint(f);
  u = u + 0x7FFFu + ((u >> 16) & 1u);
  return (short)(u >> 16);
}
__device__ __forceinline__ float wred(float v){
  #pragma unroll
  for (int o = 32; o; o >>= 1) v += __shfl_xor(v, o);
  return v;
}
__device__ __forceinline__ float sigm(float x){ return 1.0f / (1.0f + __expf(-x)); }
__device__ __forceinline__ float tnh(float x){
  x = fminf(15.0f, fmaxf(-15.0f, x));
  float e = __expf(2.0f * x);
  return (e - 1.0f) / (e + 1.0f);
}
__device__ __forceinline__ float gelu(float v){
  return 0.5f * v * (1.0f + erff(v * 0.70710678118654752440f));
}

// ws layout (shorts), all matrices swizzled for coalesced B-frag loads:
// main matrices (1024x256 each): elem = s*16384 + g*4096 + kk*512 + lane*8 + j
//   where lane = q*16+m16, hid = s*16+m16, k = kk*32+q*8+j, gate-row = g*256+hid
//   [0,262144) Wih0  [262144,524288) Whh0  [524288,786432) Wih1  [786432,1048576) Whh1
// W3 [128][256]: 1048576 + s2*4096 + kk*512 + lane*8  (row = s2*16+m16)
// W4 padded [16][128]: 1081344 + kk*512 + lane*8      (row = m16, kk<4)
__global__ void prep_kernel(
    const float* __restrict__ Wih0, const float* __restrict__ Whh0,
    const float* __restrict__ Wih1, const float* __restrict__ Whh1,
    const float* __restrict__ W3,   const float* __restrict__ W4,
    short* __restrict__ wsb)
{
  const int i = blockIdx.x * 256 + threadIdx.x;
  if (i >= 1083392) return;
  float v;
  if (i < 1048576){
    const int seg = i >> 18;
    const int r   = i & 262143;
    const int s   = r >> 14;
    const int g   = (r >> 12) & 3;
    const int kk  = (r >> 9) & 7;
    const int q   = (r >> 7) & 3;
    const int m16 = (r >> 3) & 15;
    const int j   = r & 7;
    const int hid = s * 16 + m16;
    const int k   = kk * 32 + q * 8 + j;
    const float* mt = (seg == 0) ? Wih0 : (seg == 1) ? Whh0 : (seg == 2) ? Wih1 : Whh1;
    v = mt[(g * 256 + hid) * 256 + k];
  } else if (i < 1081344){
    const int r   = i - 1048576;        // 0..32767
    const int s2  = r >> 12;            // 0..7
    const int kk  = (r >> 9) & 7;
    const int q   = (r >> 7) & 3;
    const int m16 = (r >> 3) & 15;
    const int j   = r & 7;
    v = W3[(s2 * 16 + m16) * 256 + kk * 32 + q * 8 + j];
  } else {
    const int r   = i - 1081344;        // 0..2047
    const int kk  = (r >> 9) & 3;
    const int q   = (r >> 7) & 3;
    const int m16 = (r >> 3) & 15;
    const int j   = r & 7;
    const int k   = kk * 32 + q * 8 + j;
    v = (m16 < 2) ? W4[m16 * 128 + k] : 0.0f;
  }
  wsb[i] = f2bf(v);
}

__global__ __launch_bounds__(1024) void curve_main(
    const float* __restrict__ x,
    const float* __restrict__ W1, const float* __restrict__ b1,
    const float* __restrict__ g1, const float* __restrict__ be1,
    const float* __restrict__ W2, const float* __restrict__ b2,
    const float* __restrict__ g2, const float* __restrict__ be2,
    const float* __restrict__ bih0, const float* __restrict__ bhh0,
    const float* __restrict__ bih1, const float* __restrict__ bhh1,
    const float* __restrict__ b3, const float* __restrict__ b4,
    const short* __restrict__ wsb,
    float* __restrict__ out)
{
  const int tid  = threadIdx.x;
  const int w    = tid >> 6;        // wave 0..15 <-> 16-col hidden slice
  const int lane = tid & 63;
  const int q    = lane >> 4;
  const int m16  = lane & 15;
  const int row0 = blockIdx.x * 16;
  const int col  = w * 16 + m16;    // this lane's hidden column

  __shared__ __align__(16) short h0c[8 * NH];      // h0 for 8 chunk steps
  __shared__ __align__(16) short h1buf[2][NH];
  __shared__ __align__(16) short dstg[16 * DSTR];

  // --------------- encoder: wave w computes batch row row0 + w -------------
  {
    const int r = row0 + w;
    float xv[5];
    #pragma unroll
    for (int k = 0; k < 5; k++) xv[k] = x[r * 5 + k];
    float a0 = b1[lane], a1 = b1[lane + 64];
    #pragma unroll
    for (int k = 0; k < 5; k++){
      a0 += xv[k] * W1[lane * 5 + k];
      a1 += xv[k] * W1[(lane + 64) * 5 + k];
    }
    a0 = gelu(a0); a1 = gelu(a1);
    float mean = wred(a0 + a1) * (1.0f / 128.0f);
    float d0 = a0 - mean, d1 = a1 - mean;
    float inv = rsqrtf(wred(d0 * d0 + d1 * d1) * (1.0f / 128.0f) + 1e-5f);
    float y0 = d0 * inv * g1[lane]      + be1[lane];
    float y1 = d1 * inv * g1[lane + 64] + be1[lane + 64];

    float acc2[4];
    #pragma unroll
    for (int u = 0; u < 4; u++) acc2[u] = b2[lane + 64 * u];
    for (int k = 0; k < 64; k++){
      float v0 = __shfl(y0, k);
      float v1 = __shfl(y1, k);
      #pragma unroll
      for (int u = 0; u < 4; u++){
        const float* wr = W2 + (lane + 64 * u) * 128;
        acc2[u] += v0 * wr[k] + v1 * wr[k + 64];
      }
    }
    #pragma unroll
    for (int u = 0; u < 4; u++) acc2[u] = gelu(acc2[u]);
    float s = acc2[0] + acc2[1] + acc2[2] + acc2[3];
    mean = wred(s) * (1.0f / 256.0f);
    float vv = 0.0f;
    #pragma unroll
    for (int u = 0; u < 4; u++){ float d = acc2[u] - mean; vv += d * d; }
    inv = rsqrtf(wred(vv) * (1.0f / 256.0f) + 1e-5f);
    #pragma unroll
    for (int u = 0; u < 4; u++){
      int c = lane + 64 * u;
      float e = (acc2[u] - mean) * inv * g2[c] + be2[c];
      h0c[w * HSTR + c] = f2bf(e);        // enc staged in slot 0
    }
  }
  __syncthreads();

  // per-lane swizzled weight bases (1KB coalesced per frag per wave)
  const short* pwi0 = wsb            + w * 16384 + (lane << 3);
  const short* pwh0 = wsb +  262144  + w * 16384 + (lane << 3);
  const short* pwi1 = wsb +  524288  + w * 16384 + (lane << 3);
  const short* pwh1 = wsb +  786432  + w * 16384 + (lane << 3);
  const short* pw3  = wsb + 1048576  + (w & 7) * 4096 + (lane << 3);
  const short* pw4  = wsb + 1081344  + (lane << 3);

  // ---- xp0 = enc @ Wih0_slice^T + (bih0+bhh0), kept in registers ----
  f4v xp[4];
  #pragma unroll
  for (int g = 0; g < 4; g++){
    const int n = g * 256 + col;
    const float bi = bih0[n] + bhh0[n];
    f4v t = {bi, bi, bi, bi};
    xp[g] = t;
  }
  #pragma unroll
  for (int kk = 0; kk < 8; kk++){
    const s8v a = *(const s8v*)&h0c[m16 * HSTR + kk * 32 + q * 8];
    #pragma unroll
    for (int g = 0; g < 4; g++)
      xp[g] = mfma16(a, *(const s8v*)(pwi0 + g * 4096 + kk * 512), xp[g]);
  }
  __syncthreads();

  // zero h0 slot 7 (read as h0(-1)) and h1 buffers
  for (int i = tid; i < NH; i += 1024){
    h0c[7 * NH + i] = 0; h1buf[0][i] = 0; h1buf[1][i] = 0;
  }

  float bs1[4];
  #pragma unroll
  for (int g = 0; g < 4; g++){
    const int n = g * 256 + col;
    bs1[g] = bih1[n] + bhh1[n];
  }
  const float b3c = b3[(w & 7) * 16 + m16];
  const float b4v = (m16 < 2) ? b4[m16] : 0.0f;
  float c0[4] = {0, 0, 0, 0}, c1[4] = {0, 0, 0, 0};
  __syncthreads();

  // ------------------------ chunked recurrence ------------------------
  #pragma unroll 1
  for (int ch = 0; ch < 32; ch++){
    // ================= phase A: layer 0, 8 steps (stream Whh0) ============
    {
      s8v rb[4][4];                              // 4-slot ring, distance 2
      #pragma unroll
      for (int g = 0; g < 4; g++){
        rb[0][g] = *(const s8v*)(pwh0 + g * 4096);
        rb[1][g] = *(const s8v*)(pwh0 + g * 4096 + 512);
      }
      #pragma unroll 1
      for (int s = 0; s < 8; s++){
        const short* hin  = h0c + ((s == 0) ? 7 : s - 1) * NH;
        short*       hout = h0c + s * NH;
        f4v acc[4] = {xp[0], xp[1], xp[2], xp[3]};
        #pragma unroll
        for (int kk = 0; kk < 8; kk++){
          #pragma unroll
          for (int g = 0; g < 4; g++)
            rb[(kk + 2) & 3][g] =
              *(const s8v*)(pwh0 + g * 4096 + ((kk + 2) & 7) * 512);
          const s8v a = *(const s8v*)&hin[m16 * HSTR + kk * 32 + q * 8];
          #pragma unroll
          for (int g = 0; g < 4; g++)
            acc[g] = mfma16(a, rb[kk & 3][g], acc[g]);
        }
        #pragma unroll
        for (int r = 0; r < 4; r++){
          float ii = sigm(acc[0][r]);
          float ff = sigm(acc[1][r]);
          float gg = tnh (acc[2][r]);
          float oo = sigm(acc[3][r]);
          c0[r] = ff * c0[r] + ii * gg;
          hout[(q * 4 + r) * HSTR + col] = f2bf(oo * tnh(c0[r]));
        }
        __syncthreads();
      }
    }
    // ============ phase B: layer 1 + decoder (stream Wih1,Whh1,W3) ========
    {
      s8v ri[2][4], rh[2][4];                    // 2-slot rings, distance 1
      #pragma unroll
      for (int g = 0; g < 4; g++){
        ri[0][g] = *(const s8v*)(pwi1 + g * 4096);
        rh[0][g] = *(const s8v*)(pwh1 + g * 4096);
      }
      #pragma unroll 1
      for (int s = 0; s < 8; s++){
        const int t   = ch * 8 + s;
        const int cur = t & 1, nxt = cur ^ 1;
        const short* h0in = h0c + s * NH;
        f4v acc[4];
        #pragma unroll
        for (int g = 0; g < 4; g++){
          f4v tv = {bs1[g], bs1[g], bs1[g], bs1[g]};
          acc[g] = tv;
        }
        #pragma unroll
        for (int kk = 0; kk < 8; kk++){
          #pragma unroll
          for (int g = 0; g < 4; g++){
            ri[(kk + 1) & 1][g] =
              *(const s8v*)(pwi1 + g * 4096 + ((kk + 1) & 7) * 512);
            rh[(kk + 1) & 1][g] =
              *(const s8v*)(pwh1 + g * 4096 + ((kk + 1) & 7) * 512);
          }
          const s8v a0 = *(const s8v*)&h0in[m16 * HSTR + kk * 32 + q * 8];
          const s8v a1 = *(const s8v*)&h1buf[cur][m16 * HSTR + kk * 32 + q * 8];
          #pragma unroll
          for (int g = 0; g < 4; g++){
            acc[g] = mfma16(a0, ri[kk & 1][g], acc[g]);
            acc[g] = mfma16(a1, rh[kk & 1][g], acc[g]);
          }
        }
        #pragma unroll
        for (int r = 0; r < 4; r++){
          float ii = sigm(acc[0][r]);
          float ff = sigm(acc[1][r]);
          float gg = tnh (acc[2][r]);
          float oo = sigm(acc[3][r]);
          c1[r] = ff * c1[r] + ii * gg;
          h1buf[nxt][(q * 4 + r) * HSTR + col] = f2bf(oo * tnh(c1[r]));
        }
        __syncthreads();                         // h1(t) visible

        // decoder stage 1: waves 0..7, d cols (w&7)*16 + m16
        if (w < 8){
          f4v ad = {b3c, b3c, b3c, b3c};
          #pragma unroll
          for (int kk = 0; kk < 8; kk++){
            const s8v bw = *(const s8v*)(pw3 + kk * 512);
            const s8v a  = *(const s8v*)&h1buf[nxt][m16 * HSTR + kk * 32 + q * 8];
            ad = mfma16(a, bw, ad);
          }
          #pragma unroll
          for (int r = 0; r < 4; r++)
            dstg[(q * 4 + r) * DSTR + (w & 7) * 16 + m16] = f2bf(gelu(ad[r]));
        }
        __syncthreads();                         // d visible

        // decoder stage 2: wave 0 -> out
        if (w == 0){
          f4v ao = {0.f, 0.f, 0.f, 0.f};
          #pragma unroll
          for (int kk = 0; kk < 4; kk++){
            const s8v bw = *(const s8v*)(pw4 + kk * 512);
            const s8v a  = *(const s8v*)&dstg[m16 * DSTR + kk * 32 + q * 8];
            ao = mfma16(a, bw, ao);
          }
          if (m16 < 2){
            #pragma unroll
            for (int r = 0; r < 4; r++)
              out[((size_t)(row0 + q * 4 + r) * 256 + t) * 2 + m16] = ao[r] + b4v;
          }
        }
      }
    }
  }
}

extern "C" void kernel_launch(void* const* d_in, const int* in_sizes, int n_in,
                              void* d_out, int out_size, void* d_ws, size_t ws_size,
                              hipStream_t stream)
{
  const float* x    = (const float*)d_in[0];
  const float* W1   = (const float*)d_in[1];
  const float* b1   = (const float*)d_in[2];
  const float* g1   = (const float*)d_in[3];
  const float* be1  = (const float*)d_in[4];
  const float* W2   = (const float*)d_in[5];
  const float* b2   = (const float*)d_in[6];
  const float* g2   = (const float*)d_in[7];
  const float* be2  = (const float*)d_in[8];
  const float* Wih0 = (const float*)d_in[9];
  const float* Whh0 = (const float*)d_in[10];
  const float* bih0 = (const float*)d_in[11];
  const float* bhh0 = (const float*)d_in[12];
  const float* Wih1 = (const float*)d_in[13];
  const float* Whh1 = (const float*)d_in[14];
  const float* bih1 = (const float*)d_in[15];
  const float* bhh1 = (const float*)d_in[16];
  const float* W3   = (const float*)d_in[17];
  const float* b3   = (const float*)d_in[18];
  const float* W4   = (const float*)d_in[19];
  const float* b4   = (const float*)d_in[20];

  short* wsb = (short*)d_ws;

  prep_kernel<<<4232, 256, 0, stream>>>(Wih0, Whh0, Wih1, Whh1, W3, W4, wsb);
  curve_main<<<128, 1024, 0, stream>>>(x, W1, b1, g1, be1, W2, b2, g2, be2,
                                       bih0, bhh0, bih1, bhh1, b3, b4, wsb,
                                       (float*)d_out);
}